// Round 1
// 4622.531 us; speedup vs baseline: 1.6259x; 1.6259x over previous
//
#include <hip/hip_runtime.h>

// TreePool on MI355X — round 1 of polish session 2.
//
// Bottleneck analysis (rocprof): feat_kernel 2283us @ VALUBusy 11%, HBM 1%
// => latency-bound from 64-line weight-row gathers (lane=q mapping) + 1
// node/block.  Same gather pathology in bm_gemm / lstm_level.  signal_kernel
// burned ~250us of debug delay.
//
// New pipeline (f32-ws fast path):
//   probe -> init_decode (weights -> f32/bf16, transposed, in ws)
//         -> feat_fast  (wave-serial nodes, W^T columns in VGPRs, pred rows
//                        via uniform scalar loads, masked rows skipped)
//         -> bm_fast    (lane=j, coalesced W^T[k][j][4], bitmap via s_load)
//         -> 16x lstm_fast<MC> (gate-interleaved W^T[k][u][4], x via s_load,
//                        h0 in LDS broadcast; MC=nodes/block shrinks for
//                        small levels)
//         -> heads.
// Old kernels retained as fallback when ws is too small for f32 + weights.

#define NNODES 65535
#define DMAX 15

typedef unsigned short u16;
typedef unsigned int u32;
typedef unsigned char u8;

// decoded-weights area layout (floats, relative to wbase = C + N*256)
#define OFF_PRED 0          // W_pred^T  [p][q]        4096
#define OFF_OP 4096         // W_op row-major f32      1024
#define OFF_BOP 5120        // b_op                    32
#define OFF_BPRED 5152      // b_pred                  64
#define OFF_BBM 5216        // b_bm                    128
#define OFF_B4 5344         // (b_ih+b_hh)[u][q]       1024
#define OFF_WTB 6368        // W_bm^T [k4][j][4]       128000
#define OFF_IH 134368       // W_ih^T [k][u][4q]       294912 slots (u16 if fm)
#define OFF_HH 429280       // W_hh^T [k][u][4q]       262144 slots
#define OFF_TOTAL 691424

__device__ __forceinline__ float bf2f(u16 b) { return __uint_as_float(((u32)b) << 16); }
__device__ __forceinline__ u16 f2bf(float f) {
    u32 u = __float_as_uint(f);
    return (u16)((u + 0x7fffu + ((u >> 16) & 1u)) >> 16);
}
__device__ __forceinline__ float sigm(float x) { return 1.0f / (1.0f + expf(-x)); }

// mode-generic loads -----------------------------------------------------
__device__ __forceinline__ float ldf(const void* p, size_t i, int fm) {
    return fm ? bf2f(((const u16*)p)[i]) : ((const float*)p)[i];
}
__device__ __forceinline__ bool ldmask(const void* p, size_t i, int mm) {
    if (mm == 0) return ((const int*)p)[i] != 0;
    if (mm == 1) return ((const u8*)p)[i] != 0;
    if (mm == 2) return ((const u16*)p)[i] != 0;
    return ((const float*)p)[i] != 0.0f;
}
__device__ __forceinline__ float4 ldw4(const void* W, size_t off, int fm) {
    if (fm) {
        uint2 v = *(const uint2*)((const u16*)W + off);
        return make_float4(bf2f((u16)(v.x & 0xffffu)), bf2f((u16)(v.x >> 16)),
                           bf2f((u16)(v.y & 0xffffu)), bf2f((u16)(v.y >> 16)));
    }
    return *(const float4*)((const float*)W + off);
}
__device__ __forceinline__ float dot_w(const void* W, size_t off, const float* xs, int n8, int fm) {
    float acc = 0.0f;
    if (fm) {
        const uint4* w4 = (const uint4*)((const u16*)W + off);
        for (int it = 0; it < n8; ++it) {
            uint4 v = w4[it]; const float* p = xs + it * 8;
            acc += bf2f((u16)(v.x & 0xffffu)) * p[0] + bf2f((u16)(v.x >> 16)) * p[1]
                 + bf2f((u16)(v.y & 0xffffu)) * p[2] + bf2f((u16)(v.y >> 16)) * p[3]
                 + bf2f((u16)(v.z & 0xffffu)) * p[4] + bf2f((u16)(v.z >> 16)) * p[5]
                 + bf2f((u16)(v.w & 0xffffu)) * p[6] + bf2f((u16)(v.w >> 16)) * p[7];
        }
    } else {
        const float4* w4 = (const float4*)((const float*)W + off);
        for (int it = 0; it < n8; ++it) {
            float4 a = w4[2 * it], b = w4[2 * it + 1]; const float* p = xs + it * 8;
            acc += a.x*p[0] + a.y*p[1] + a.z*p[2] + a.w*p[3]
                 + b.x*p[4] + b.y*p[5] + b.z*p[6] + b.w*p[7];
        }
    }
    return acc;
}

// storage (workspace) load/store overloads -------------------------------
__device__ __forceinline__ float lds_(const float* p, size_t i) { return p[i]; }
__device__ __forceinline__ float lds_(const u16* p, size_t i) { return bf2f(p[i]); }
__device__ __forceinline__ void sts_(float* p, size_t i, float v) { p[i] = v; }
__device__ __forceinline__ void sts_(u16* p, size_t i, float v) { p[i] = f2bf(v); }

// ------------------------------------------------------------------------
// dtype probe: flags[0]=fmode (1=bf16,0=f32), flags[1]=mmode
// ------------------------------------------------------------------------
__global__ void probe_kernel(const void* a0, const void* a1, const void* a2,
                             const void* m0, const void* m1, int* flags) {
    if (threadIdx.x != 0 || blockIdx.x != 0) return;
    const void* arrs[3] = {a0, a1, a2};
    int good = 0;
    for (int a = 0; a < 3; ++a) {
        const u32* w = (const u32*)arrs[a];
        for (int i = 0; i < 64; ++i) {
            float f = __uint_as_float((w[i] & 0xFFFFu) << 16);
            float af = fabsf(f);
            if (af >= 1.52587890625e-05f && af <= 65536.0f) good++;
        }
    }
    int fm = (good >= 96) ? 1 : 0;

    bool i32ok = true, f32ok = true, bf16ok = true, u8ok = true;
    const u32* ms[2] = {(const u32*)m0, (const u32*)m1};
    for (int a = 0; a < 2; ++a) {
        for (int i = 0; i < 64; ++i) {
            u32 x = ms[a][i];
            if (!(x == 0u || x == 1u)) i32ok = false;
            if (!(x == 0u || x == 0x3F800000u)) f32ok = false;
            u32 lo = x & 0xFFFFu, hi = x >> 16;
            if (!((lo == 0u || lo == 0x3F80u) && (hi == 0u || hi == 0x3F80u))) bf16ok = false;
            if (!(((x & 0xFFu) <= 1u) && (((x >> 8) & 0xFFu) <= 1u) &&
                  (((x >> 16) & 0xFFu) <= 1u) && ((x >> 24) <= 1u))) u8ok = false;
        }
    }
    int mm = i32ok ? 0 : (f32ok ? 3 : (bf16ok ? 2 : (u8ok ? 1 : 0)));
    flags[0] = fm;
    flags[1] = mm;
}

// ------------------------------------------------------------------------
// init_decode: one-time weight decode + transpose into ws (fast path only).
// ------------------------------------------------------------------------
__global__ __launch_bounds__(256) void init_decode(
    const void* __restrict__ W_op, const void* __restrict__ b_op,
    const void* __restrict__ W_pred, const void* __restrict__ b_pred,
    const void* __restrict__ W_bm, const void* __restrict__ b_bm,
    const void* __restrict__ W_ih, const void* __restrict__ b_ih,
    const void* __restrict__ W_hh, const void* __restrict__ b_hh,
    float* __restrict__ wbase, const int* __restrict__ flags)
{
    const int fm = flags[0];
    const int tid = blockIdx.x * 256 + threadIdx.x;
    const int nT = gridDim.x * 256;

    for (int i = tid; i < 4096; i += nT) {              // W_pred^T[p][q]
        int p = i >> 6, q = i & 63;
        wbase[OFF_PRED + i] = ldf(W_pred, (size_t)q * 64 + p, fm);
    }
    for (int i = tid; i < 1024; i += nT) wbase[OFF_OP + i] = ldf(W_op, i, fm);
    for (int i = tid; i < 32; i += nT)   wbase[OFF_BOP + i] = ldf(b_op, i, fm);
    for (int i = tid; i < 64; i += nT)   wbase[OFF_BPRED + i] = ldf(b_pred, i, fm);
    for (int i = tid; i < 128; i += nT)  wbase[OFF_BBM + i] = ldf(b_bm, i, fm);
    for (int i = tid; i < 1024; i += nT) {              // (b_ih+b_hh)[u][q]
        int uu = i >> 2, q = i & 3;
        wbase[OFF_B4 + i] = ldf(b_ih, q * 256 + uu, fm) + ldf(b_hh, q * 256 + uu, fm);
    }
    for (int i = tid; i < 128000; i += nT) {            // W_bm^T [k4][j][4]
        int kk = i & 3, r = i >> 2;
        int jj = r & 127, k4 = r >> 7;
        wbase[OFF_WTB + i] = ldf(W_bm, (size_t)jj * 1000 + k4 * 4 + kk, fm);
    }
    // LSTM weights: gate-interleaved transpose [k][u][4q]; keep bf16 bits when
    // fm=1 (bit-exact, halves L2 traffic in the k-loop), f32 otherwise.
    if (fm) {
        u16* dI = (u16*)(wbase + OFF_IH);
        const u16* sI = (const u16*)W_ih;
        for (int i = tid; i < 294912; i += nT) {
            int q = i & 3, r = i >> 2, uu = r & 255, k = r >> 8;
            dI[i] = sI[(size_t)(q * 256 + uu) * 288 + k];
        }
        u16* dH = (u16*)(wbase + OFF_HH);
        const u16* sH = (const u16*)W_hh;
        for (int i = tid; i < 262144; i += nT) {
            int q = i & 3, r = i >> 2, uu = r & 255, k = r >> 8;
            dH[i] = sH[(size_t)(q * 256 + uu) * 256 + k];
        }
    } else {
        float* dI = wbase + OFF_IH;
        const float* sI = (const float*)W_ih;
        for (int i = tid; i < 294912; i += nT) {
            int q = i & 3, r = i >> 2, uu = r & 255, k = r >> 8;
            dI[i] = sI[(size_t)(q * 256 + uu) * 288 + k];
        }
        float* dH = wbase + OFF_HH;
        const float* sH = (const float*)W_hh;
        for (int i = tid; i < 262144; i += nT) {
            int q = i & 3, r = i >> 2, uu = r & 255, k = r >> 8;
            dH[i] = sH[(size_t)(q * 256 + uu) * 256 + k];
        }
    }
}

// ------------------------------------------------------------------------
// feat_fast: wave-serial over nodes. lane = output q; W_pred^T column in
// VGPRs; pred rows via block-uniform (scalar) loads; masked rows skipped;
// pooling entirely in registers. No LDS, no barriers.
// ------------------------------------------------------------------------
__device__ __forceinline__ u32 maskbits8(const void* mask, int n, int mm) {
    u32 b = 0;
    if (mm == 0) {
        const int* p = (const int*)mask + (size_t)n * 8;
#pragma unroll
        for (int k = 0; k < 8; ++k) b |= (p[k] != 0 ? 1u : 0u) << k;
    } else if (mm == 1) {
        const u8* p = (const u8*)mask + (size_t)n * 8;
#pragma unroll
        for (int k = 0; k < 8; ++k) b |= (p[k] != 0 ? 1u : 0u) << k;
    } else if (mm == 2) {
        const u16* p = (const u16*)mask + (size_t)n * 8;
#pragma unroll
        for (int k = 0; k < 8; ++k) b |= (p[k] != 0 ? 1u : 0u) << k;
    } else {
        const float* p = (const float*)mask + (size_t)n * 8;
#pragma unroll
        for (int k = 0; k < 8; ++k) b |= (p[k] != 0.0f ? 1u : 0u) << k;
    }
    return b;
}

__global__ __launch_bounds__(256) void feat_fast(
    const void* __restrict__ op_vec,
    const void* __restrict__ c1_preds, const void* __restrict__ c1_mask, const void* __restrict__ c1_and,
    const void* __restrict__ c2_preds, const void* __restrict__ c2_mask, const void* __restrict__ c2_and,
    const float* __restrict__ wpredT, const float* __restrict__ wopR,
    const float* __restrict__ f_bop, const float* __restrict__ f_bpred,
    float* __restrict__ x_out, const int* __restrict__ flags)
{
    const int fm = flags[0], mm = flags[1];
    const int lane = threadIdx.x & 63;
    const int gw = blockIdx.x * 4 + (threadIdx.x >> 6);
    const int NW = gridDim.x * 4;

    float wq[64];            // W_pred[q=lane][p] for all p — coalesced load
#pragma unroll
    for (int p = 0; p < 64; ++p) wq[p] = wpredT[p * 64 + lane];
    float wop[32];           // W_op[o=lane&31][p]
#pragma unroll
    for (int p = 0; p < 32; ++p) wop[p] = wopR[(lane & 31) * 32 + p];
    const float bq = f_bpred[lane];
    const float bo = f_bop[lane & 31];

    for (int n = gw; n < NNODES; n += NW) {
        // op projection (lanes 32..63 compute duplicates, only <32 store)
        float accop = bo;
        if (fm) {
            const uint4* ov = (const uint4*)((const u16*)op_vec + (size_t)n * 32);
#pragma unroll
            for (int i = 0; i < 4; ++i) {
                uint4 v = ov[i];
                accop += __uint_as_float(v.x << 16)         * wop[8*i+0];
                accop += __uint_as_float(v.x & 0xffff0000u) * wop[8*i+1];
                accop += __uint_as_float(v.y << 16)         * wop[8*i+2];
                accop += __uint_as_float(v.y & 0xffff0000u) * wop[8*i+3];
                accop += __uint_as_float(v.z << 16)         * wop[8*i+4];
                accop += __uint_as_float(v.z & 0xffff0000u) * wop[8*i+5];
                accop += __uint_as_float(v.w << 16)         * wop[8*i+6];
                accop += __uint_as_float(v.w & 0xffff0000u) * wop[8*i+7];
            }
        } else {
            const float4* ov = (const float4*)((const float*)op_vec + (size_t)n * 32);
#pragma unroll
            for (int i = 0; i < 8; ++i) {
                float4 v = ov[i];
                accop += v.x * wop[4*i+0]; accop += v.y * wop[4*i+1];
                accop += v.z * wop[4*i+2]; accop += v.w * wop[4*i+3];
            }
        }
        if (lane < 32) x_out[(size_t)n * 288 + lane] = accop;

#pragma unroll
        for (int c = 0; c < 2; ++c) {
            const void* preds = c ? c2_preds : c1_preds;
            const void* mask  = c ? c2_mask  : c1_mask;
            const void* andp  = c ? c2_and   : c1_and;
            const u32 mb = maskbits8(mask, n, mm);
            float mn = 1e30f, mx = -1e30f;
            for (int k = 0; k < 8; ++k) {
                if (!((mb >> k) & 1)) continue;   // uniform skip: ~50% of rows
                float e = bq;
                if (fm) {
                    const uint4* pr = (const uint4*)((const u16*)preds + ((size_t)n * 8 + k) * 64);
#pragma unroll
                    for (int i = 0; i < 8; ++i) {
                        uint4 v = pr[i];
                        e += __uint_as_float(v.x << 16)         * wq[8*i+0];
                        e += __uint_as_float(v.x & 0xffff0000u) * wq[8*i+1];
                        e += __uint_as_float(v.y << 16)         * wq[8*i+2];
                        e += __uint_as_float(v.y & 0xffff0000u) * wq[8*i+3];
                        e += __uint_as_float(v.z << 16)         * wq[8*i+4];
                        e += __uint_as_float(v.z & 0xffff0000u) * wq[8*i+5];
                        e += __uint_as_float(v.w << 16)         * wq[8*i+6];
                        e += __uint_as_float(v.w & 0xffff0000u) * wq[8*i+7];
                    }
                } else {
                    const float4* pr = (const float4*)((const float*)preds + ((size_t)n * 8 + k) * 64);
#pragma unroll
                    for (int i = 0; i < 16; ++i) {
                        float4 v = pr[i];
                        e += v.x * wq[4*i+0]; e += v.y * wq[4*i+1];
                        e += v.z * wq[4*i+2]; e += v.w * wq[4*i+3];
                    }
                }
                mn = fminf(mn, e); mx = fmaxf(mx, e);
            }
            bool is_and = ldmask(andp, n, mm);
            float pooled = (mb != 0) ? (is_and ? mn : mx) : 0.0f;
            x_out[(size_t)n * 288 + 32 + c * 64 + lane] = pooled;
        }
    }
}

// ------------------------------------------------------------------------
// bm_fast: x[n][160+j] = bitmap[n] . W_bm[j] + b_bm[j]. lane = j (coalesced
// W^T loads); bitmap rows block-uniform (scalar loads); 32 nodes/thread.
// ------------------------------------------------------------------------
__global__ __launch_bounds__(256) void bm_fast(
    const void* __restrict__ bitmap, const float* __restrict__ WTb,
    const float* __restrict__ f_bbm, float* __restrict__ x_out,
    const int* __restrict__ flags)
{
    const int fm = flags[0];
    const int t = threadIdx.x;
    const int j = t & 127;
    const int half = t >> 7;
    const int nb = blockIdx.x * 64 + half * 32;
    int mc = NNODES - nb; if (mc > 32) mc = 32;

    float acc[32];
#pragma unroll
    for (int m = 0; m < 32; ++m) acc[m] = 0.0f;

    if (fm) {
        const u32* bp = (const u32*)bitmap;
        for (int k4 = 0; k4 < 250; ++k4) {
            float4 w = *(const float4*)&WTb[(size_t)(k4 * 128 + j) * 4];
#pragma unroll
            for (int m = 0; m < 32; ++m) {
                if (m < mc) {
                    size_t base = ((size_t)(nb + m) * 1000 + k4 * 4) >> 1;
                    u32 a0 = bp[base], a1 = bp[base + 1];
                    acc[m] += __uint_as_float(a0 << 16) * w.x;
                    acc[m] += __uint_as_float(a0 & 0xffff0000u) * w.y;
                    acc[m] += __uint_as_float(a1 << 16) * w.z;
                    acc[m] += __uint_as_float(a1 & 0xffff0000u) * w.w;
                }
            }
        }
    } else {
        const float* bpf = (const float*)bitmap;
        for (int k4 = 0; k4 < 250; ++k4) {
            float4 w = *(const float4*)&WTb[(size_t)(k4 * 128 + j) * 4];
#pragma unroll
            for (int m = 0; m < 32; ++m) {
                if (m < mc) {
                    float4 a = *(const float4*)&bpf[(size_t)(nb + m) * 1000 + k4 * 4];
                    acc[m] += a.x * w.x; acc[m] += a.y * w.y;
                    acc[m] += a.z * w.z; acc[m] += a.w * w.w;
                }
            }
        }
    }
    const float bj = f_bbm[j];
#pragma unroll
    for (int m = 0; m < 32; ++m)
        if (m < mc) x_out[(size_t)(nb + m) * 288 + 160 + j] = acc[m] + bj;
}

// ------------------------------------------------------------------------
// lstm_fast<MC>: MC nodes/block, thread u=t owns hidden unit u for 4 gates.
// Weight loads coalesced uint2/float4 from gate-interleaved W^T; x via
// uniform scalar loads; h0 staged in LDS (broadcast b128 reads); c0 direct.
// ------------------------------------------------------------------------
__device__ __forceinline__ void ldw4g16(float w[4][4], const u16* W, int k4, int u) {
#pragma unroll
    for (int kk = 0; kk < 4; ++kk) {
        uint2 v = *(const uint2*)(W + ((size_t)(k4 * 4 + kk) * 256 + u) * 4);
        w[kk][0] = __uint_as_float(v.x << 16);
        w[kk][1] = __uint_as_float(v.x & 0xffff0000u);
        w[kk][2] = __uint_as_float(v.y << 16);
        w[kk][3] = __uint_as_float(v.y & 0xffff0000u);
    }
}
__device__ __forceinline__ void ldw4g32(float w[4][4], const float* W, int k4, int u) {
#pragma unroll
    for (int kk = 0; kk < 4; ++kk) {
        float4 v = *(const float4*)(W + ((size_t)(k4 * 4 + kk) * 256 + u) * 4);
        w[kk][0] = v.x; w[kk][1] = v.y; w[kk][2] = v.z; w[kk][3] = v.w;
    }
}

template <int MC>
__global__ __launch_bounds__(256) void lstm_fast(
    const float* __restrict__ x, const void* __restrict__ WTih,
    const void* __restrict__ WThh, const float* __restrict__ b4,
    float* __restrict__ H, float* __restrict__ C,
    int start, int isLeaf, const int* __restrict__ flags)
{
    const int u = threadIdx.x;
    const int node0 = start + blockIdx.x * MC;
    __shared__ float h0s[MC][256];

    if (!isLeaf) {
        for (int idx = threadIdx.x; idx < MC * 256; idx += 256) {
            int m = idx >> 8, k = idx & 255;
            int ci = 2 * (node0 + m) - NNODES;
            h0s[m][k] = 0.5f * (H[(size_t)ci * 256 + k] + H[(size_t)(ci - 1) * 256 + k]);
        }
        __syncthreads();
    }
    const int fm = flags[0];

    float4 bb = *(const float4*)&b4[u * 4];
    float acc[MC][4];
#pragma unroll
    for (int m = 0; m < MC; ++m) { acc[m][0] = bb.x; acc[m][1] = bb.y; acc[m][2] = bb.z; acc[m][3] = bb.w; }

    if (fm) {
        const u16* W = (const u16*)WTih;
        for (int k4 = 0; k4 < 72; ++k4) {
            float w[4][4]; ldw4g16(w, W, k4, u);
#pragma unroll
            for (int m = 0; m < MC; ++m) {
                float4 a = *(const float4*)&x[(size_t)(node0 + m) * 288 + k4 * 4];
#pragma unroll
                for (int q = 0; q < 4; ++q)
                    acc[m][q] += a.x * w[0][q] + a.y * w[1][q] + a.z * w[2][q] + a.w * w[3][q];
            }
        }
        if (!isLeaf) {
            const u16* Wh = (const u16*)WThh;
            for (int k4 = 0; k4 < 64; ++k4) {
                float w[4][4]; ldw4g16(w, Wh, k4, u);
#pragma unroll
                for (int m = 0; m < MC; ++m) {
                    float4 a = *(const float4*)&h0s[m][k4 * 4];
#pragma unroll
                    for (int q = 0; q < 4; ++q)
                        acc[m][q] += a.x * w[0][q] + a.y * w[1][q] + a.z * w[2][q] + a.w * w[3][q];
                }
            }
        }
    } else {
        const float* W = (const float*)WTih;
        for (int k4 = 0; k4 < 72; ++k4) {
            float w[4][4]; ldw4g32(w, W, k4, u);
#pragma unroll
            for (int m = 0; m < MC; ++m) {
                float4 a = *(const float4*)&x[(size_t)(node0 + m) * 288 + k4 * 4];
#pragma unroll
                for (int q = 0; q < 4; ++q)
                    acc[m][q] += a.x * w[0][q] + a.y * w[1][q] + a.z * w[2][q] + a.w * w[3][q];
            }
        }
        if (!isLeaf) {
            const float* Wh = (const float*)WThh;
            for (int k4 = 0; k4 < 64; ++k4) {
                float w[4][4]; ldw4g32(w, Wh, k4, u);
#pragma unroll
                for (int m = 0; m < MC; ++m) {
                    float4 a = *(const float4*)&h0s[m][k4 * 4];
#pragma unroll
                    for (int q = 0; q < 4; ++q)
                        acc[m][q] += a.x * w[0][q] + a.y * w[1][q] + a.z * w[2][q] + a.w * w[3][q];
                }
            }
        }
    }

#pragma unroll
    for (int m = 0; m < MC; ++m) {
        int node = node0 + m;
        float c0 = 0.0f;
        if (!isLeaf) {
            int ci = 2 * node - NNODES;
            c0 = 0.5f * (C[(size_t)ci * 256 + u] + C[(size_t)(ci - 1) * 256 + u]);
        }
        float cn = sigm(acc[m][1]) * c0 + sigm(acc[m][0]) * tanhf(acc[m][2]);
        float hn = sigm(acc[m][3]) * tanhf(cn);
        H[(size_t)node * 256 + u] = hn;
        C[(size_t)node * 256 + u] = cn;
    }
}

// ------------------------------------------------------------------------
// OLD kernels (fallback paths when ws can't hold f32 state + weights)
// ------------------------------------------------------------------------
template <typename ST>
__global__ __launch_bounds__(256) void feat_kernel(
    const void* op_vec,
    const void* c1_preds, const void* c1_mask, const void* c1_and,
    const void* c2_preds, const void* c2_mask, const void* c2_and,
    const void* W_op, const void* b_op, const void* W_pred, const void* b_pred,
    ST* __restrict__ x_out, const int* __restrict__ flags)
{
    const int n = blockIdx.x, t = threadIdx.x;
    __shared__ int s_fm, s_mm;
    __shared__ float sh_preds[512];
    __shared__ float e_sh[512];
    __shared__ float xrow[160];
    if (t == 0) { s_fm = flags[0]; s_mm = flags[1]; }
    __syncthreads();
    const int fm = s_fm, mm = s_mm;

    if (t < 32) {
        float acc = ldf(b_op, t, fm);
        for (int p = 0; p < 32; ++p)
            acc += ldf(op_vec, (size_t)n * 32 + p, fm) * ldf(W_op, (size_t)t * 32 + p, fm);
        xrow[t] = acc;
    }

    for (int c = 0; c < 2; ++c) {
        const void* preds = c ? c2_preds : c1_preds;
        const void* mask  = c ? c2_mask  : c1_mask;
        const void* andp  = c ? c2_and   : c1_and;
        __syncthreads();
        sh_preds[t]       = ldf(preds, (size_t)n * 512 + t, fm);
        sh_preds[t + 256] = ldf(preds, (size_t)n * 512 + t + 256, fm);
        __syncthreads();
        for (int w = t; w < 512; w += 256) {
            int k = w >> 6, q = w & 63;
            e_sh[w] = ldf(b_pred, q, fm) + dot_w(W_pred, (size_t)q * 64, sh_preds + k * 64, 8, fm);
        }
        __syncthreads();
        if (t < 64) {
            bool anym = false;
            float mn = 1e30f, mx = -1e30f;
            for (int k = 0; k < 8; ++k) {
                if (ldmask(mask, (size_t)n * 8 + k, mm)) {
                    anym = true;
                    float v = e_sh[k * 64 + t];
                    mn = fminf(mn, v); mx = fmaxf(mx, v);
                }
            }
            xrow[32 + c * 64 + t] = anym ? (ldmask(andp, n, mm) ? mn : mx) : 0.0f;
        }
    }
    __syncthreads();
    for (int p = t; p < 160; p += 256) sts_(x_out, (size_t)n * 288 + p, xrow[p]);
}

template <typename ST>
__global__ __launch_bounds__(256) void bm_gemm(
    const void* bitmap, const void* W_bm, const void* b_bm,
    ST* __restrict__ x_out, const int* __restrict__ flags)
{
    const int t = threadIdx.x;
    const int nb = blockIdx.x * 16;
    __shared__ int s_fm;
    __shared__ float bmt[16][1000];
    if (t == 0) s_fm = flags[0];
    __syncthreads();
    const int fm = s_fm;

    for (int m = 0; m < 16; ++m) {
        int node = nb + m;
        for (int k = t; k < 1000; k += 256)
            bmt[m][k] = (node < NNODES) ? ldf(bitmap, (size_t)node * 1000 + k, fm) : 0.0f;
    }
    __syncthreads();

    const int j = (t & 63) * 2;
    const int mg = t >> 6;
    float acc[4][2];
#pragma unroll
    for (int m = 0; m < 4; ++m) { acc[m][0] = 0.0f; acc[m][1] = 0.0f; }

    for (int k4 = 0; k4 < 250; ++k4) {
        float4 w0 = ldw4(W_bm, (size_t)j * 1000 + k4 * 4, fm);
        float4 w1 = ldw4(W_bm, (size_t)(j + 1) * 1000 + k4 * 4, fm);
#pragma unroll
        for (int m = 0; m < 4; ++m) {
            float4 a = *(const float4*)&bmt[mg * 4 + m][k4 * 4];
            acc[m][0] += a.x * w0.x + a.y * w0.y + a.z * w0.z + a.w * w0.w;
            acc[m][1] += a.x * w1.x + a.y * w1.y + a.z * w1.z + a.w * w1.w;
        }
    }
    float b0 = ldf(b_bm, j, fm), b1 = ldf(b_bm, j + 1, fm);
#pragma unroll
    for (int m = 0; m < 4; ++m) {
        int node = nb + mg * 4 + m;
        if (node < NNODES) {
            sts_(x_out, (size_t)node * 288 + 160 + j,     acc[m][0] + b0);
            sts_(x_out, (size_t)node * 288 + 160 + j + 1, acc[m][1] + b1);
        }
    }
}

template <typename ST>
__global__ __launch_bounds__(256) void lstm_level(
    const ST* __restrict__ x, const void* W_ih, const void* b_ih,
    const void* W_hh, const void* b_hh,
    ST* __restrict__ H, ST* __restrict__ C,
    int start, int count, int isLeaf, const int* __restrict__ flags)
{
    const int t = threadIdx.x;
    const int nb = blockIdx.x * 16;
    __shared__ int s_fm;
    __shared__ float xs[16][288];
    __shared__ float h0s[16][256];
    __shared__ float c0s[16][256];
    if (t == 0) s_fm = flags[0];

    for (int m = 0; m < 16; ++m) {
        int idx = nb + m;
        int node = start + idx;
        bool v = idx < count;
        for (int k = t; k < 288; k += 256)
            xs[m][k] = v ? lds_(x, (size_t)node * 288 + k) : 0.0f;
        if (!isLeaf) {
            if (v) {
                int ci = 2 * node - NNODES;
                h0s[m][t] = 0.5f * (lds_(H, (size_t)ci * 256 + t) + lds_(H, (size_t)(ci - 1) * 256 + t));
                c0s[m][t] = 0.5f * (lds_(C, (size_t)ci * 256 + t) + lds_(C, (size_t)(ci - 1) * 256 + t));
            } else { h0s[m][t] = 0.0f; c0s[m][t] = 0.0f; }
        }
    }
    __syncthreads();
    const int fm = s_fm;
    const int u = t;

    float acc[16][4];
#pragma unroll
    for (int q = 0; q < 4; ++q) {
        float b = ldf(b_ih, q * 256 + u, fm) + ldf(b_hh, q * 256 + u, fm);
#pragma unroll
        for (int m = 0; m < 16; ++m) acc[m][q] = b;
    }

    for (int k4 = 0; k4 < 72; ++k4) {
        float4 w[4];
#pragma unroll
        for (int q = 0; q < 4; ++q) w[q] = ldw4(W_ih, (size_t)(q * 256 + u) * 288 + k4 * 4, fm);
#pragma unroll
        for (int m = 0; m < 16; ++m) {
            float4 a = *(const float4*)&xs[m][k4 * 4];
#pragma unroll
            for (int q = 0; q < 4; ++q)
                acc[m][q] += a.x * w[q].x + a.y * w[q].y + a.z * w[q].z + a.w * w[q].w;
        }
    }
    if (!isLeaf) {
        for (int k4 = 0; k4 < 64; ++k4) {
            float4 w[4];
#pragma unroll
            for (int q = 0; q < 4; ++q) w[q] = ldw4(W_hh, (size_t)(q * 256 + u) * 256 + k4 * 4, fm);
#pragma unroll
            for (int m = 0; m < 16; ++m) {
                float4 a = *(const float4*)&h0s[m][k4 * 4];
#pragma unroll
                for (int q = 0; q < 4; ++q)
                    acc[m][q] += a.x * w[q].x + a.y * w[q].y + a.z * w[q].z + a.w * w[q].w;
            }
        }
    }
#pragma unroll
    for (int m = 0; m < 16; ++m) {
        int idx = nb + m;
        if (idx < count) {
            int node = start + idx;
            float c0 = isLeaf ? 0.0f : c0s[m][t];
            float cn = sigm(acc[m][1]) * c0 + sigm(acc[m][0]) * tanhf(acc[m][2]);
            float hn = sigm(acc[m][3]) * tanhf(cn);
            sts_(H, (size_t)node * 256 + t, hn);
            sts_(C, (size_t)node * 256 + t, cn);
        }
    }
}

template <typename ST>
__global__ __launch_bounds__(256) void heads_kernel(
    const ST* __restrict__ H,
    const void* W2a, const void* b2a, const void* W3a, const void* b3a,
    const void* Woa, const void* boa,
    const void* W2b, const void* b2b, const void* W3b, const void* b3b,
    const void* Wob, const void* bob,
    void* out, const int* __restrict__ flags)
{
    const int t = threadIdx.x, head = t >> 7, j = t & 127;
    __shared__ int s_fm;
    __shared__ float hs[256];
    __shared__ float t1[2][128];
    __shared__ float t2[2][128];
    if (t == 0) s_fm = flags[0];
    hs[t] = lds_(H, (size_t)(NNODES - 1) * 256 + t);
    __syncthreads();
    const int fm = s_fm;

    const void* W2 = head ? W2b : W2a; const void* b2 = head ? b2b : b2a;
    const void* W3 = head ? W3b : W3a; const void* b3 = head ? b3b : b3a;
    const void* Wo = head ? Wob : Woa; const void* bo = head ? bob : boa;

    float acc = ldf(b2, j, fm) + dot_w(W2, (size_t)j * 256, hs, 32, fm);
    t1[head][j] = fmaxf(acc, 0.0f);
    __syncthreads();
    acc = ldf(b3, j, fm) + dot_w(W3, (size_t)j * 128, t1[head], 16, fm);
    t2[head][j] = fmaxf(acc, 0.0f);
    __syncthreads();
    if (j == 0) {
        float s = ldf(bo, 0, fm);
        for (int p = 0; p < 128; ++p) s += t2[head][p] * ldf(Wo, p, fm);
        float r = sigm(s);
        if (fm) ((u16*)out)[head] = f2bf(r);
        else    ((float*)out)[head] = r;
    }
}

// ------------------------------------------------------------------------
template <typename ST>
static void run_pipeline(void* const* d_in, void* d_out, void* d_ws,
                         const int* flags, hipStream_t stream) {
    ST* x = (ST*)d_ws;
    ST* H = x + (size_t)NNODES * 288;
    ST* C = H + (size_t)NNODES * 256;

    feat_kernel<ST><<<NNODES, 256, 0, stream>>>(
        d_in[0], d_in[1], d_in[2], d_in[3], d_in[4], d_in[5], d_in[6],
        d_in[8], d_in[9], d_in[10], d_in[11], x, flags);
    bm_gemm<ST><<<(NNODES + 15) / 16, 256, 0, stream>>>(
        d_in[7], d_in[12], d_in[13], x, flags);
    for (int d = DMAX; d >= 0; --d) {
        int count = 1 << d;
        int start = NNODES - (1 << (d + 1)) + 1;
        int blocks = (count + 15) / 16;
        lstm_level<ST><<<blocks, 256, 0, stream>>>(
            x, d_in[14], d_in[15], d_in[16], d_in[17], H, C,
            start, count, (d == DMAX) ? 1 : 0, flags);
    }
    heads_kernel<ST><<<1, 256, 0, stream>>>(
        H, d_in[18], d_in[19], d_in[20], d_in[21], d_in[22], d_in[23],
        d_in[24], d_in[25], d_in[26], d_in[27], d_in[28], d_in[29],
        d_out, flags);
}

// nodes/block per level: keep per-wave k-loop cost proportional to real work
// (small levels were paying full 16-node cost before) while keeping >=128
// blocks for machine fill on mid levels. All values divide count exactly.
static int pick_mc(int count) {
    if (count >= 8192) return 16;
    if (count >= 2048) return 8;
    if (count >= 1024) return 4;
    if (count >= 256)  return 2;
    return 1;
}

static void run_fast(void* const* d_in, void* d_out, void* d_ws,
                     const int* flags, hipStream_t stream) {
    float* x = (float*)d_ws;
    float* H = x + (size_t)NNODES * 288;
    float* C = H + (size_t)NNODES * 256;
    float* wb = C + (size_t)NNODES * 256;

    init_decode<<<512, 256, 0, stream>>>(
        d_in[8], d_in[9], d_in[10], d_in[11], d_in[12], d_in[13],
        d_in[14], d_in[15], d_in[16], d_in[17], wb, flags);
    feat_fast<<<1024, 256, 0, stream>>>(
        d_in[0], d_in[1], d_in[2], d_in[3], d_in[4], d_in[5], d_in[6],
        wb + OFF_PRED, wb + OFF_OP, wb + OFF_BOP, wb + OFF_BPRED, x, flags);
    bm_fast<<<1024, 256, 0, stream>>>(d_in[7], wb + OFF_WTB, wb + OFF_BBM, x, flags);

    for (int d = DMAX; d >= 0; --d) {
        int count = 1 << d;
        int start = NNODES - (1 << (d + 1)) + 1;
        int isLeaf = (d == DMAX) ? 1 : 0;
        int mc = pick_mc(count);
        int blocks = count / mc;
        switch (mc) {
        case 16: lstm_fast<16><<<blocks, 256, 0, stream>>>(x, wb + OFF_IH, wb + OFF_HH, wb + OFF_B4, H, C, start, isLeaf, flags); break;
        case 8:  lstm_fast<8><<<blocks, 256, 0, stream>>>(x, wb + OFF_IH, wb + OFF_HH, wb + OFF_B4, H, C, start, isLeaf, flags); break;
        case 4:  lstm_fast<4><<<blocks, 256, 0, stream>>>(x, wb + OFF_IH, wb + OFF_HH, wb + OFF_B4, H, C, start, isLeaf, flags); break;
        case 2:  lstm_fast<2><<<blocks, 256, 0, stream>>>(x, wb + OFF_IH, wb + OFF_HH, wb + OFF_B4, H, C, start, isLeaf, flags); break;
        default: lstm_fast<1><<<blocks, 256, 0, stream>>>(x, wb + OFF_IH, wb + OFF_HH, wb + OFF_B4, H, C, start, isLeaf, flags); break;
        }
    }
    heads_kernel<float><<<1, 256, 0, stream>>>(
        H, d_in[18], d_in[19], d_in[20], d_in[21], d_in[22], d_in[23],
        d_in[24], d_in[25], d_in[26], d_in[27], d_in[28], d_in[29],
        d_out, flags);
}

extern "C" void kernel_launch(void* const* d_in, const int* in_sizes, int n_in,
                              void* d_out, int out_size, void* d_ws, size_t ws_size,
                              hipStream_t stream) {
    size_t foff = (ws_size - 64) & ~(size_t)63;     // flags at 64B-aligned tail
    int* flags = (int*)((char*)d_ws + foff);

    probe_kernel<<<1, 1, 0, stream>>>(d_in[0], d_in[14], d_in[7], d_in[2], d_in[3], flags);

    const size_t XHC  = (size_t)NNODES * 800 * 4;   // x+H+C in f32
    const size_t WTOT = (size_t)OFF_TOTAL * 4;      // decoded weights
    if (foff >= XHC + WTOT)  run_fast(d_in, d_out, d_ws, flags, stream);
    else if (foff >= XHC)    run_pipeline<float>(d_in, d_out, d_ws, flags, stream);
    else                     run_pipeline<u16>(d_in, d_out, d_ws, flags, stream);
}

// Round 2
// 2575.140 us; speedup vs baseline: 2.9186x; 1.7951x over previous
//
#include <hip/hip_runtime.h>

// TreePool on MI355X — round 2 of polish session 2.
//
// R1: feat 2283us -> fast (latency fix). R2 target: bm_fast 2357us @ VALU 20%:
// wave-uniform bitmap addresses compiled to s_load pairs (16k scalar loads /
// thread, lgkmcnt-serialized). bm_fast2 stages the bitmap tile via coalesced
// per-lane uint4 loads -> LDS, computes from LDS broadcast reads (8 nodes x
// 2 j-cols per thread, FMA:LDS = 8:1) against coalesced W^T[k4][j][4] rows.
//
// Pipeline (f32-ws fast path):
//   probe -> init_decode -> feat_fast -> bm_fast2 -> 16x lstm_fast<MC> -> heads

#define NNODES 65535
#define DMAX 15

typedef unsigned short u16;
typedef unsigned int u32;
typedef unsigned char u8;

// decoded-weights area layout (floats, relative to wbase = C + N*256)
#define OFF_PRED 0          // W_pred^T  [p][q]        4096
#define OFF_OP 4096         // W_op row-major f32      1024
#define OFF_BOP 5120        // b_op                    32
#define OFF_BPRED 5152      // b_pred                  64
#define OFF_BBM 5216        // b_bm                    128
#define OFF_B4 5344         // (b_ih+b_hh)[u][q]       1024
#define OFF_WTB 6368        // W_bm^T [k4<256][j][4]   131072 (zero-pad k>=1000)
#define OFF_IH 137440       // W_ih^T [k][u][4q]       294912 slots (u16 if fm)
#define OFF_HH 432352       // W_hh^T [k][u][4q]       262144 slots
#define OFF_TOTAL 694496

__device__ __forceinline__ float bf2f(u16 b) { return __uint_as_float(((u32)b) << 16); }
__device__ __forceinline__ u16 f2bf(float f) {
    u32 u = __float_as_uint(f);
    return (u16)((u + 0x7fffu + ((u >> 16) & 1u)) >> 16);
}
__device__ __forceinline__ float sigm(float x) { return 1.0f / (1.0f + expf(-x)); }

// mode-generic loads -----------------------------------------------------
__device__ __forceinline__ float ldf(const void* p, size_t i, int fm) {
    return fm ? bf2f(((const u16*)p)[i]) : ((const float*)p)[i];
}
__device__ __forceinline__ bool ldmask(const void* p, size_t i, int mm) {
    if (mm == 0) return ((const int*)p)[i] != 0;
    if (mm == 1) return ((const u8*)p)[i] != 0;
    if (mm == 2) return ((const u16*)p)[i] != 0;
    return ((const float*)p)[i] != 0.0f;
}
__device__ __forceinline__ float4 ldw4(const void* W, size_t off, int fm) {
    if (fm) {
        uint2 v = *(const uint2*)((const u16*)W + off);
        return make_float4(bf2f((u16)(v.x & 0xffffu)), bf2f((u16)(v.x >> 16)),
                           bf2f((u16)(v.y & 0xffffu)), bf2f((u16)(v.y >> 16)));
    }
    return *(const float4*)((const float*)W + off);
}
__device__ __forceinline__ float dot_w(const void* W, size_t off, const float* xs, int n8, int fm) {
    float acc = 0.0f;
    if (fm) {
        const uint4* w4 = (const uint4*)((const u16*)W + off);
        for (int it = 0; it < n8; ++it) {
            uint4 v = w4[it]; const float* p = xs + it * 8;
            acc += bf2f((u16)(v.x & 0xffffu)) * p[0] + bf2f((u16)(v.x >> 16)) * p[1]
                 + bf2f((u16)(v.y & 0xffffu)) * p[2] + bf2f((u16)(v.y >> 16)) * p[3]
                 + bf2f((u16)(v.z & 0xffffu)) * p[4] + bf2f((u16)(v.z >> 16)) * p[5]
                 + bf2f((u16)(v.w & 0xffffu)) * p[6] + bf2f((u16)(v.w >> 16)) * p[7];
        }
    } else {
        const float4* w4 = (const float4*)((const float*)W + off);
        for (int it = 0; it < n8; ++it) {
            float4 a = w4[2 * it], b = w4[2 * it + 1]; const float* p = xs + it * 8;
            acc += a.x*p[0] + a.y*p[1] + a.z*p[2] + a.w*p[3]
                 + b.x*p[4] + b.y*p[5] + b.z*p[6] + b.w*p[7];
        }
    }
    return acc;
}

// storage (workspace) load/store overloads -------------------------------
__device__ __forceinline__ float lds_(const float* p, size_t i) { return p[i]; }
__device__ __forceinline__ float lds_(const u16* p, size_t i) { return bf2f(p[i]); }
__device__ __forceinline__ void sts_(float* p, size_t i, float v) { p[i] = v; }
__device__ __forceinline__ void sts_(u16* p, size_t i, float v) { p[i] = f2bf(v); }

// ------------------------------------------------------------------------
// dtype probe: flags[0]=fmode (1=bf16,0=f32), flags[1]=mmode
// ------------------------------------------------------------------------
__global__ void probe_kernel(const void* a0, const void* a1, const void* a2,
                             const void* m0, const void* m1, int* flags) {
    if (threadIdx.x != 0 || blockIdx.x != 0) return;
    const void* arrs[3] = {a0, a1, a2};
    int good = 0;
    for (int a = 0; a < 3; ++a) {
        const u32* w = (const u32*)arrs[a];
        for (int i = 0; i < 64; ++i) {
            float f = __uint_as_float((w[i] & 0xFFFFu) << 16);
            float af = fabsf(f);
            if (af >= 1.52587890625e-05f && af <= 65536.0f) good++;
        }
    }
    int fm = (good >= 96) ? 1 : 0;

    bool i32ok = true, f32ok = true, bf16ok = true, u8ok = true;
    const u32* ms[2] = {(const u32*)m0, (const u32*)m1};
    for (int a = 0; a < 2; ++a) {
        for (int i = 0; i < 64; ++i) {
            u32 x = ms[a][i];
            if (!(x == 0u || x == 1u)) i32ok = false;
            if (!(x == 0u || x == 0x3F800000u)) f32ok = false;
            u32 lo = x & 0xFFFFu, hi = x >> 16;
            if (!((lo == 0u || lo == 0x3F80u) && (hi == 0u || hi == 0x3F80u))) bf16ok = false;
            if (!(((x & 0xFFu) <= 1u) && (((x >> 8) & 0xFFu) <= 1u) &&
                  (((x >> 16) & 0xFFu) <= 1u) && ((x >> 24) <= 1u))) u8ok = false;
        }
    }
    int mm = i32ok ? 0 : (f32ok ? 3 : (bf16ok ? 2 : (u8ok ? 1 : 0)));
    flags[0] = fm;
    flags[1] = mm;
}

// ------------------------------------------------------------------------
// init_decode: one-time weight decode + transpose into ws (fast path only).
// ------------------------------------------------------------------------
__global__ __launch_bounds__(256) void init_decode(
    const void* __restrict__ W_op, const void* __restrict__ b_op,
    const void* __restrict__ W_pred, const void* __restrict__ b_pred,
    const void* __restrict__ W_bm, const void* __restrict__ b_bm,
    const void* __restrict__ W_ih, const void* __restrict__ b_ih,
    const void* __restrict__ W_hh, const void* __restrict__ b_hh,
    float* __restrict__ wbase, const int* __restrict__ flags)
{
    const int fm = flags[0];
    const int tid = blockIdx.x * 256 + threadIdx.x;
    const int nT = gridDim.x * 256;

    for (int i = tid; i < 4096; i += nT) {              // W_pred^T[p][q]
        int p = i >> 6, q = i & 63;
        wbase[OFF_PRED + i] = ldf(W_pred, (size_t)q * 64 + p, fm);
    }
    for (int i = tid; i < 1024; i += nT) wbase[OFF_OP + i] = ldf(W_op, i, fm);
    for (int i = tid; i < 32; i += nT)   wbase[OFF_BOP + i] = ldf(b_op, i, fm);
    for (int i = tid; i < 64; i += nT)   wbase[OFF_BPRED + i] = ldf(b_pred, i, fm);
    for (int i = tid; i < 128; i += nT)  wbase[OFF_BBM + i] = ldf(b_bm, i, fm);
    for (int i = tid; i < 1024; i += nT) {              // (b_ih+b_hh)[u][q]
        int uu = i >> 2, q = i & 3;
        wbase[OFF_B4 + i] = ldf(b_ih, q * 256 + uu, fm) + ldf(b_hh, q * 256 + uu, fm);
    }
    for (int i = tid; i < 131072; i += nT) {            // W_bm^T [k4][j][4], k-padded
        int kk = i & 3, r = i >> 2;
        int jj = r & 127, k4 = r >> 7;
        int k = k4 * 4 + kk;
        wbase[OFF_WTB + i] = (k < 1000) ? ldf(W_bm, (size_t)jj * 1000 + k, fm) : 0.0f;
    }
    // LSTM weights: gate-interleaved transpose [k][u][4q]; keep bf16 bits when
    // fm=1 (bit-exact, halves L2 traffic in the k-loop), f32 otherwise.
    if (fm) {
        u16* dI = (u16*)(wbase + OFF_IH);
        const u16* sI = (const u16*)W_ih;
        for (int i = tid; i < 294912; i += nT) {
            int q = i & 3, r = i >> 2, uu = r & 255, k = r >> 8;
            dI[i] = sI[(size_t)(q * 256 + uu) * 288 + k];
        }
        u16* dH = (u16*)(wbase + OFF_HH);
        const u16* sH = (const u16*)W_hh;
        for (int i = tid; i < 262144; i += nT) {
            int q = i & 3, r = i >> 2, uu = r & 255, k = r >> 8;
            dH[i] = sH[(size_t)(q * 256 + uu) * 256 + k];
        }
    } else {
        float* dI = wbase + OFF_IH;
        const float* sI = (const float*)W_ih;
        for (int i = tid; i < 294912; i += nT) {
            int q = i & 3, r = i >> 2, uu = r & 255, k = r >> 8;
            dI[i] = sI[(size_t)(q * 256 + uu) * 288 + k];
        }
        float* dH = wbase + OFF_HH;
        const float* sH = (const float*)W_hh;
        for (int i = tid; i < 262144; i += nT) {
            int q = i & 3, r = i >> 2, uu = r & 255, k = r >> 8;
            dH[i] = sH[(size_t)(q * 256 + uu) * 256 + k];
        }
    }
}

// ------------------------------------------------------------------------
// feat_fast: wave-serial over nodes. lane = output q; W_pred^T column in
// VGPRs; pred rows via block-uniform (scalar) loads; masked rows skipped;
// pooling entirely in registers. No LDS, no barriers.
// ------------------------------------------------------------------------
__device__ __forceinline__ u32 maskbits8(const void* mask, int n, int mm) {
    u32 b = 0;
    if (mm == 0) {
        const int* p = (const int*)mask + (size_t)n * 8;
#pragma unroll
        for (int k = 0; k < 8; ++k) b |= (p[k] != 0 ? 1u : 0u) << k;
    } else if (mm == 1) {
        const u8* p = (const u8*)mask + (size_t)n * 8;
#pragma unroll
        for (int k = 0; k < 8; ++k) b |= (p[k] != 0 ? 1u : 0u) << k;
    } else if (mm == 2) {
        const u16* p = (const u16*)mask + (size_t)n * 8;
#pragma unroll
        for (int k = 0; k < 8; ++k) b |= (p[k] != 0 ? 1u : 0u) << k;
    } else {
        const float* p = (const float*)mask + (size_t)n * 8;
#pragma unroll
        for (int k = 0; k < 8; ++k) b |= (p[k] != 0.0f ? 1u : 0u) << k;
    }
    return b;
}

__global__ __launch_bounds__(256) void feat_fast(
    const void* __restrict__ op_vec,
    const void* __restrict__ c1_preds, const void* __restrict__ c1_mask, const void* __restrict__ c1_and,
    const void* __restrict__ c2_preds, const void* __restrict__ c2_mask, const void* __restrict__ c2_and,
    const float* __restrict__ wpredT, const float* __restrict__ wopR,
    const float* __restrict__ f_bop, const float* __restrict__ f_bpred,
    float* __restrict__ x_out, const int* __restrict__ flags)
{
    const int fm = flags[0], mm = flags[1];
    const int lane = threadIdx.x & 63;
    const int gw = blockIdx.x * 4 + (threadIdx.x >> 6);
    const int NW = gridDim.x * 4;

    float wq[64];            // W_pred[q=lane][p] for all p — coalesced load
#pragma unroll
    for (int p = 0; p < 64; ++p) wq[p] = wpredT[p * 64 + lane];
    float wop[32];           // W_op[o=lane&31][p]
#pragma unroll
    for (int p = 0; p < 32; ++p) wop[p] = wopR[(lane & 31) * 32 + p];
    const float bq = f_bpred[lane];
    const float bo = f_bop[lane & 31];

    for (int n = gw; n < NNODES; n += NW) {
        float accop = bo;
        if (fm) {
            const uint4* ov = (const uint4*)((const u16*)op_vec + (size_t)n * 32);
#pragma unroll
            for (int i = 0; i < 4; ++i) {
                uint4 v = ov[i];
                accop += __uint_as_float(v.x << 16)         * wop[8*i+0];
                accop += __uint_as_float(v.x & 0xffff0000u) * wop[8*i+1];
                accop += __uint_as_float(v.y << 16)         * wop[8*i+2];
                accop += __uint_as_float(v.y & 0xffff0000u) * wop[8*i+3];
                accop += __uint_as_float(v.z << 16)         * wop[8*i+4];
                accop += __uint_as_float(v.z & 0xffff0000u) * wop[8*i+5];
                accop += __uint_as_float(v.w << 16)         * wop[8*i+6];
                accop += __uint_as_float(v.w & 0xffff0000u) * wop[8*i+7];
            }
        } else {
            const float4* ov = (const float4*)((const float*)op_vec + (size_t)n * 32);
#pragma unroll
            for (int i = 0; i < 8; ++i) {
                float4 v = ov[i];
                accop += v.x * wop[4*i+0]; accop += v.y * wop[4*i+1];
                accop += v.z * wop[4*i+2]; accop += v.w * wop[4*i+3];
            }
        }
        if (lane < 32) x_out[(size_t)n * 288 + lane] = accop;

#pragma unroll
        for (int c = 0; c < 2; ++c) {
            const void* preds = c ? c2_preds : c1_preds;
            const void* mask  = c ? c2_mask  : c1_mask;
            const void* andp  = c ? c2_and   : c1_and;
            const u32 mb = maskbits8(mask, n, mm);
            float mn = 1e30f, mx = -1e30f;
            for (int k = 0; k < 8; ++k) {
                if (!((mb >> k) & 1)) continue;   // uniform skip: ~50% of rows
                float e = bq;
                if (fm) {
                    const uint4* pr = (const uint4*)((const u16*)preds + ((size_t)n * 8 + k) * 64);
#pragma unroll
                    for (int i = 0; i < 8; ++i) {
                        uint4 v = pr[i];
                        e += __uint_as_float(v.x << 16)         * wq[8*i+0];
                        e += __uint_as_float(v.x & 0xffff0000u) * wq[8*i+1];
                        e += __uint_as_float(v.y << 16)         * wq[8*i+2];
                        e += __uint_as_float(v.y & 0xffff0000u) * wq[8*i+3];
                        e += __uint_as_float(v.z << 16)         * wq[8*i+4];
                        e += __uint_as_float(v.z & 0xffff0000u) * wq[8*i+5];
                        e += __uint_as_float(v.w << 16)         * wq[8*i+6];
                        e += __uint_as_float(v.w & 0xffff0000u) * wq[8*i+7];
                    }
                } else {
                    const float4* pr = (const float4*)((const float*)preds + ((size_t)n * 8 + k) * 64);
#pragma unroll
                    for (int i = 0; i < 16; ++i) {
                        float4 v = pr[i];
                        e += v.x * wq[4*i+0]; e += v.y * wq[4*i+1];
                        e += v.z * wq[4*i+2]; e += v.w * wq[4*i+3];
                    }
                }
                mn = fminf(mn, e); mx = fmaxf(mx, e);
            }
            bool is_and = ldmask(andp, n, mm);
            float pooled = (mb != 0) ? (is_and ? mn : mx) : 0.0f;
            x_out[(size_t)n * 288 + 32 + c * 64 + lane] = pooled;
        }
    }
}

// ------------------------------------------------------------------------
// bm_fast2: x[n][160+j] = bitmap[n].W_bm[j] + b_bm[j].
// Block tile: 32 nodes x 128 j. Bitmap staged via coalesced per-lane uint4
// loads -> LDS f32 (4 k-chunks of 256, weights zero-padded past k=1000).
// Thread = 2 j-cols x 8 nodes (16 acc): 64 FMA per 8 broadcast ds_read_b128.
// ------------------------------------------------------------------------
#define BM_KT 256

__global__ __launch_bounds__(256) void bm_fast2(
    const void* __restrict__ bitmap, const float* __restrict__ WTb,
    const float* __restrict__ f_bbm, float* __restrict__ x_out,
    const int* __restrict__ flags)
{
    const int fm = flags[0];
    const int t = threadIdx.x;
    const int nb = blockIdx.x * 32;
    __shared__ float bmt[32][BM_KT];

    const int j0 = t & 63;          // outputs j0 and j0+64
    const int mq = t >> 6;          // wave-uniform node quarter: nodes mq*8..+7

    float acc[8][2];
#pragma unroll
    for (int m = 0; m < 8; ++m) { acc[m][0] = 0.0f; acc[m][1] = 0.0f; }

    for (int kc = 0; kc < 4; ++kc) {
        __syncthreads();
        // stage 32 nodes x 256 k into LDS (f32), 16B coalesced global loads
        for (int e = t * 8; e < 32 * BM_KT; e += 256 * 8) {
            int row = e >> 8;
            int k = e & (BM_KT - 1);
            int gk = kc * BM_KT + k;
            int node = nb + row;
            float f[8];
            if (gk < 1000 && node < NNODES) {
                if (fm) {
                    uint4 v = *(const uint4*)((const u16*)bitmap + (size_t)node * 1000 + gk);
                    f[0] = __uint_as_float(v.x << 16); f[1] = __uint_as_float(v.x & 0xffff0000u);
                    f[2] = __uint_as_float(v.y << 16); f[3] = __uint_as_float(v.y & 0xffff0000u);
                    f[4] = __uint_as_float(v.z << 16); f[5] = __uint_as_float(v.z & 0xffff0000u);
                    f[6] = __uint_as_float(v.w << 16); f[7] = __uint_as_float(v.w & 0xffff0000u);
                } else {
                    const float4* pf = (const float4*)((const float*)bitmap + (size_t)node * 1000 + gk);
                    float4 a = pf[0], b = pf[1];
                    f[0]=a.x; f[1]=a.y; f[2]=a.z; f[3]=a.w;
                    f[4]=b.x; f[5]=b.y; f[6]=b.z; f[7]=b.w;
                }
            } else {
#pragma unroll
                for (int i = 0; i < 8; ++i) f[i] = 0.0f;
            }
            *(float4*)&bmt[row][k]     = make_float4(f[0], f[1], f[2], f[3]);
            *(float4*)&bmt[row][k + 4] = make_float4(f[4], f[5], f[6], f[7]);
        }
        __syncthreads();

        const float* wrow = WTb + (size_t)kc * 64 * 128 * 4;
        for (int k4 = 0; k4 < 64; ++k4) {
            float4 w0 = *(const float4*)&wrow[((size_t)k4 * 128 + j0) * 4];
            float4 w1 = *(const float4*)&wrow[((size_t)k4 * 128 + j0 + 64) * 4];
#pragma unroll
            for (int m = 0; m < 8; ++m) {
                float4 a = *(const float4*)&bmt[mq * 8 + m][k4 * 4];
                acc[m][0] += a.x*w0.x + a.y*w0.y + a.z*w0.z + a.w*w0.w;
                acc[m][1] += a.x*w1.x + a.y*w1.y + a.z*w1.z + a.w*w1.w;
            }
        }
    }
    const float b0 = f_bbm[j0], b1 = f_bbm[j0 + 64];
#pragma unroll
    for (int m = 0; m < 8; ++m) {
        int node = nb + mq * 8 + m;
        if (node < NNODES) {
            x_out[(size_t)node * 288 + 160 + j0]      = acc[m][0] + b0;
            x_out[(size_t)node * 288 + 160 + j0 + 64] = acc[m][1] + b1;
        }
    }
}

// ------------------------------------------------------------------------
// lstm_fast<MC>: MC nodes/block, thread u=t owns hidden unit u for 4 gates.
// ------------------------------------------------------------------------
__device__ __forceinline__ void ldw4g16(float w[4][4], const u16* W, int k4, int u) {
#pragma unroll
    for (int kk = 0; kk < 4; ++kk) {
        uint2 v = *(const uint2*)(W + ((size_t)(k4 * 4 + kk) * 256 + u) * 4);
        w[kk][0] = __uint_as_float(v.x << 16);
        w[kk][1] = __uint_as_float(v.x & 0xffff0000u);
        w[kk][2] = __uint_as_float(v.y << 16);
        w[kk][3] = __uint_as_float(v.y & 0xffff0000u);
    }
}
__device__ __forceinline__ void ldw4g32(float w[4][4], const float* W, int k4, int u) {
#pragma unroll
    for (int kk = 0; kk < 4; ++kk) {
        float4 v = *(const float4*)(W + ((size_t)(k4 * 4 + kk) * 256 + u) * 4);
        w[kk][0] = v.x; w[kk][1] = v.y; w[kk][2] = v.z; w[kk][3] = v.w;
    }
}

template <int MC>
__global__ __launch_bounds__(256) void lstm_fast(
    const float* __restrict__ x, const void* __restrict__ WTih,
    const void* __restrict__ WThh, const float* __restrict__ b4,
    float* __restrict__ H, float* __restrict__ C,
    int start, int isLeaf, const int* __restrict__ flags)
{
    const int u = threadIdx.x;
    const int node0 = start + blockIdx.x * MC;
    __shared__ float h0s[MC][256];

    if (!isLeaf) {
        for (int idx = threadIdx.x; idx < MC * 256; idx += 256) {
            int m = idx >> 8, k = idx & 255;
            int ci = 2 * (node0 + m) - NNODES;
            h0s[m][k] = 0.5f * (H[(size_t)ci * 256 + k] + H[(size_t)(ci - 1) * 256 + k]);
        }
        __syncthreads();
    }
    const int fm = flags[0];

    float4 bb = *(const float4*)&b4[u * 4];
    float acc[MC][4];
#pragma unroll
    for (int m = 0; m < MC; ++m) { acc[m][0] = bb.x; acc[m][1] = bb.y; acc[m][2] = bb.z; acc[m][3] = bb.w; }

    if (fm) {
        const u16* W = (const u16*)WTih;
        for (int k4 = 0; k4 < 72; ++k4) {
            float w[4][4]; ldw4g16(w, W, k4, u);
#pragma unroll
            for (int m = 0; m < MC; ++m) {
                float4 a = *(const float4*)&x[(size_t)(node0 + m) * 288 + k4 * 4];
#pragma unroll
                for (int q = 0; q < 4; ++q)
                    acc[m][q] += a.x * w[0][q] + a.y * w[1][q] + a.z * w[2][q] + a.w * w[3][q];
            }
        }
        if (!isLeaf) {
            const u16* Wh = (const u16*)WThh;
            for (int k4 = 0; k4 < 64; ++k4) {
                float w[4][4]; ldw4g16(w, Wh, k4, u);
#pragma unroll
                for (int m = 0; m < MC; ++m) {
                    float4 a = *(const float4*)&h0s[m][k4 * 4];
#pragma unroll
                    for (int q = 0; q < 4; ++q)
                        acc[m][q] += a.x * w[0][q] + a.y * w[1][q] + a.z * w[2][q] + a.w * w[3][q];
                }
            }
        }
    } else {
        const float* W = (const float*)WTih;
        for (int k4 = 0; k4 < 72; ++k4) {
            float w[4][4]; ldw4g32(w, W, k4, u);
#pragma unroll
            for (int m = 0; m < MC; ++m) {
                float4 a = *(const float4*)&x[(size_t)(node0 + m) * 288 + k4 * 4];
#pragma unroll
                for (int q = 0; q < 4; ++q)
                    acc[m][q] += a.x * w[0][q] + a.y * w[1][q] + a.z * w[2][q] + a.w * w[3][q];
            }
        }
        if (!isLeaf) {
            const float* Wh = (const float*)WThh;
            for (int k4 = 0; k4 < 64; ++k4) {
                float w[4][4]; ldw4g32(w, Wh, k4, u);
#pragma unroll
                for (int m = 0; m < MC; ++m) {
                    float4 a = *(const float4*)&h0s[m][k4 * 4];
#pragma unroll
                    for (int q = 0; q < 4; ++q)
                        acc[m][q] += a.x * w[0][q] + a.y * w[1][q] + a.z * w[2][q] + a.w * w[3][q];
                }
            }
        }
    }

#pragma unroll
    for (int m = 0; m < MC; ++m) {
        int node = node0 + m;
        float c0 = 0.0f;
        if (!isLeaf) {
            int ci = 2 * node - NNODES;
            c0 = 0.5f * (C[(size_t)ci * 256 + u] + C[(size_t)(ci - 1) * 256 + u]);
        }
        float cn = sigm(acc[m][1]) * c0 + sigm(acc[m][0]) * tanhf(acc[m][2]);
        float hn = sigm(acc[m][3]) * tanhf(cn);
        H[(size_t)node * 256 + u] = hn;
        C[(size_t)node * 256 + u] = cn;
    }
}

// ------------------------------------------------------------------------
// OLD kernels (fallback paths when ws can't hold f32 state + weights)
// ------------------------------------------------------------------------
template <typename ST>
__global__ __launch_bounds__(256) void feat_kernel(
    const void* op_vec,
    const void* c1_preds, const void* c1_mask, const void* c1_and,
    const void* c2_preds, const void* c2_mask, const void* c2_and,
    const void* W_op, const void* b_op, const void* W_pred, const void* b_pred,
    ST* __restrict__ x_out, const int* __restrict__ flags)
{
    const int n = blockIdx.x, t = threadIdx.x;
    __shared__ int s_fm, s_mm;
    __shared__ float sh_preds[512];
    __shared__ float e_sh[512];
    __shared__ float xrow[160];
    if (t == 0) { s_fm = flags[0]; s_mm = flags[1]; }
    __syncthreads();
    const int fm = s_fm, mm = s_mm;

    if (t < 32) {
        float acc = ldf(b_op, t, fm);
        for (int p = 0; p < 32; ++p)
            acc += ldf(op_vec, (size_t)n * 32 + p, fm) * ldf(W_op, (size_t)t * 32 + p, fm);
        xrow[t] = acc;
    }

    for (int c = 0; c < 2; ++c) {
        const void* preds = c ? c2_preds : c1_preds;
        const void* mask  = c ? c2_mask  : c1_mask;
        const void* andp  = c ? c2_and   : c1_and;
        __syncthreads();
        sh_preds[t]       = ldf(preds, (size_t)n * 512 + t, fm);
        sh_preds[t + 256] = ldf(preds, (size_t)n * 512 + t + 256, fm);
        __syncthreads();
        for (int w = t; w < 512; w += 256) {
            int k = w >> 6, q = w & 63;
            e_sh[w] = ldf(b_pred, q, fm) + dot_w(W_pred, (size_t)q * 64, sh_preds + k * 64, 8, fm);
        }
        __syncthreads();
        if (t < 64) {
            bool anym = false;
            float mn = 1e30f, mx = -1e30f;
            for (int k = 0; k < 8; ++k) {
                if (ldmask(mask, (size_t)n * 8 + k, mm)) {
                    anym = true;
                    float v = e_sh[k * 64 + t];
                    mn = fminf(mn, v); mx = fmaxf(mx, v);
                }
            }
            xrow[32 + c * 64 + t] = anym ? (ldmask(andp, n, mm) ? mn : mx) : 0.0f;
        }
    }
    __syncthreads();
    for (int p = t; p < 160; p += 256) sts_(x_out, (size_t)n * 288 + p, xrow[p]);
}

template <typename ST>
__global__ __launch_bounds__(256) void bm_gemm(
    const void* bitmap, const void* W_bm, const void* b_bm,
    ST* __restrict__ x_out, const int* __restrict__ flags)
{
    const int t = threadIdx.x;
    const int nb = blockIdx.x * 16;
    __shared__ int s_fm;
    __shared__ float bmt[16][1000];
    if (t == 0) s_fm = flags[0];
    __syncthreads();
    const int fm = s_fm;

    for (int m = 0; m < 16; ++m) {
        int node = nb + m;
        for (int k = t; k < 1000; k += 256)
            bmt[m][k] = (node < NNODES) ? ldf(bitmap, (size_t)node * 1000 + k, fm) : 0.0f;
    }
    __syncthreads();

    const int j = (t & 63) * 2;
    const int mg = t >> 6;
    float acc[4][2];
#pragma unroll
    for (int m = 0; m < 4; ++m) { acc[m][0] = 0.0f; acc[m][1] = 0.0f; }

    for (int k4 = 0; k4 < 250; ++k4) {
        float4 w0 = ldw4(W_bm, (size_t)j * 1000 + k4 * 4, fm);
        float4 w1 = ldw4(W_bm, (size_t)(j + 1) * 1000 + k4 * 4, fm);
#pragma unroll
        for (int m = 0; m < 4; ++m) {
            float4 a = *(const float4*)&bmt[mg * 4 + m][k4 * 4];
            acc[m][0] += a.x * w0.x + a.y * w0.y + a.z * w0.z + a.w * w0.w;
            acc[m][1] += a.x * w1.x + a.y * w1.y + a.z * w1.z + a.w * w1.w;
        }
    }
    float b0 = ldf(b_bm, j, fm), b1 = ldf(b_bm, j + 1, fm);
#pragma unroll
    for (int m = 0; m < 4; ++m) {
        int node = nb + mg * 4 + m;
        if (node < NNODES) {
            sts_(x_out, (size_t)node * 288 + 160 + j,     acc[m][0] + b0);
            sts_(x_out, (size_t)node * 288 + 160 + j + 1, acc[m][1] + b1);
        }
    }
}

template <typename ST>
__global__ __launch_bounds__(256) void lstm_level(
    const ST* __restrict__ x, const void* W_ih, const void* b_ih,
    const void* W_hh, const void* b_hh,
    ST* __restrict__ H, ST* __restrict__ C,
    int start, int count, int isLeaf, const int* __restrict__ flags)
{
    const int t = threadIdx.x;
    const int nb = blockIdx.x * 16;
    __shared__ int s_fm;
    __shared__ float xs[16][288];
    __shared__ float h0s[16][256];
    __shared__ float c0s[16][256];
    if (t == 0) s_fm = flags[0];

    for (int m = 0; m < 16; ++m) {
        int idx = nb + m;
        int node = start + idx;
        bool v = idx < count;
        for (int k = t; k < 288; k += 256)
            xs[m][k] = v ? lds_(x, (size_t)node * 288 + k) : 0.0f;
        if (!isLeaf) {
            if (v) {
                int ci = 2 * node - NNODES;
                h0s[m][t] = 0.5f * (lds_(H, (size_t)ci * 256 + t) + lds_(H, (size_t)(ci - 1) * 256 + t));
                c0s[m][t] = 0.5f * (lds_(C, (size_t)ci * 256 + t) + lds_(C, (size_t)(ci - 1) * 256 + t));
            } else { h0s[m][t] = 0.0f; c0s[m][t] = 0.0f; }
        }
    }
    __syncthreads();
    const int fm = s_fm;
    const int u = t;

    float acc[16][4];
#pragma unroll
    for (int q = 0; q < 4; ++q) {
        float b = ldf(b_ih, q * 256 + u, fm) + ldf(b_hh, q * 256 + u, fm);
#pragma unroll
        for (int m = 0; m < 16; ++m) acc[m][q] = b;
    }

    for (int k4 = 0; k4 < 72; ++k4) {
        float4 w[4];
#pragma unroll
        for (int q = 0; q < 4; ++q) w[q] = ldw4(W_ih, (size_t)(q * 256 + u) * 288 + k4 * 4, fm);
#pragma unroll
        for (int m = 0; m < 16; ++m) {
            float4 a = *(const float4*)&xs[m][k4 * 4];
#pragma unroll
            for (int q = 0; q < 4; ++q)
                acc[m][q] += a.x * w[q].x + a.y * w[q].y + a.z * w[q].z + a.w * w[q].w;
        }
    }
    if (!isLeaf) {
        for (int k4 = 0; k4 < 64; ++k4) {
            float4 w[4];
#pragma unroll
            for (int q = 0; q < 4; ++q) w[q] = ldw4(W_hh, (size_t)(q * 256 + u) * 256 + k4 * 4, fm);
#pragma unroll
            for (int m = 0; m < 16; ++m) {
                float4 a = *(const float4*)&h0s[m][k4 * 4];
#pragma unroll
                for (int q = 0; q < 4; ++q)
                    acc[m][q] += a.x * w[q].x + a.y * w[q].y + a.z * w[q].z + a.w * w[q].w;
            }
        }
    }
#pragma unroll
    for (int m = 0; m < 16; ++m) {
        int idx = nb + m;
        if (idx < count) {
            int node = start + idx;
            float c0 = isLeaf ? 0.0f : c0s[m][t];
            float cn = sigm(acc[m][1]) * c0 + sigm(acc[m][0]) * tanhf(acc[m][2]);
            float hn = sigm(acc[m][3]) * tanhf(cn);
            sts_(H, (size_t)node * 256 + t, hn);
            sts_(C, (size_t)node * 256 + t, cn);
        }
    }
}

template <typename ST>
__global__ __launch_bounds__(256) void heads_kernel(
    const ST* __restrict__ H,
    const void* W2a, const void* b2a, const void* W3a, const void* b3a,
    const void* Woa, const void* boa,
    const void* W2b, const void* b2b, const void* W3b, const void* b3b,
    const void* Wob, const void* bob,
    void* out, const int* __restrict__ flags)
{
    const int t = threadIdx.x, head = t >> 7, j = t & 127;
    __shared__ int s_fm;
    __shared__ float hs[256];
    __shared__ float t1[2][128];
    __shared__ float t2[2][128];
    if (t == 0) s_fm = flags[0];
    hs[t] = lds_(H, (size_t)(NNODES - 1) * 256 + t);
    __syncthreads();
    const int fm = s_fm;

    const void* W2 = head ? W2b : W2a; const void* b2 = head ? b2b : b2a;
    const void* W3 = head ? W3b : W3a; const void* b3 = head ? b3b : b3a;
    const void* Wo = head ? Wob : Woa; const void* bo = head ? bob : boa;

    float acc = ldf(b2, j, fm) + dot_w(W2, (size_t)j * 256, hs, 32, fm);
    t1[head][j] = fmaxf(acc, 0.0f);
    __syncthreads();
    acc = ldf(b3, j, fm) + dot_w(W3, (size_t)j * 128, t1[head], 16, fm);
    t2[head][j] = fmaxf(acc, 0.0f);
    __syncthreads();
    if (j == 0) {
        float s = ldf(bo, 0, fm);
        for (int p = 0; p < 128; ++p) s += t2[head][p] * ldf(Wo, p, fm);
        float r = sigm(s);
        if (fm) ((u16*)out)[head] = f2bf(r);
        else    ((float*)out)[head] = r;
    }
}

// ------------------------------------------------------------------------
template <typename ST>
static void run_pipeline(void* const* d_in, void* d_out, void* d_ws,
                         const int* flags, hipStream_t stream) {
    ST* x = (ST*)d_ws;
    ST* H = x + (size_t)NNODES * 288;
    ST* C = H + (size_t)NNODES * 256;

    feat_kernel<ST><<<NNODES, 256, 0, stream>>>(
        d_in[0], d_in[1], d_in[2], d_in[3], d_in[4], d_in[5], d_in[6],
        d_in[8], d_in[9], d_in[10], d_in[11], x, flags);
    bm_gemm<ST><<<(NNODES + 15) / 16, 256, 0, stream>>>(
        d_in[7], d_in[12], d_in[13], x, flags);
    for (int d = DMAX; d >= 0; --d) {
        int count = 1 << d;
        int start = NNODES - (1 << (d + 1)) + 1;
        int blocks = (count + 15) / 16;
        lstm_level<ST><<<blocks, 256, 0, stream>>>(
            x, d_in[14], d_in[15], d_in[16], d_in[17], H, C,
            start, count, (d == DMAX) ? 1 : 0, flags);
    }
    heads_kernel<ST><<<1, 256, 0, stream>>>(
        H, d_in[18], d_in[19], d_in[20], d_in[21], d_in[22], d_in[23],
        d_in[24], d_in[25], d_in[26], d_in[27], d_in[28], d_in[29],
        d_out, flags);
}

static int pick_mc(int count) {
    if (count >= 8192) return 16;
    if (count >= 2048) return 8;
    if (count >= 1024) return 4;
    if (count >= 256)  return 2;
    return 1;
}

static void run_fast(void* const* d_in, void* d_out, void* d_ws,
                     const int* flags, hipStream_t stream) {
    float* x = (float*)d_ws;
    float* H = x + (size_t)NNODES * 288;
    float* C = H + (size_t)NNODES * 256;
    float* wb = C + (size_t)NNODES * 256;

    init_decode<<<512, 256, 0, stream>>>(
        d_in[8], d_in[9], d_in[10], d_in[11], d_in[12], d_in[13],
        d_in[14], d_in[15], d_in[16], d_in[17], wb, flags);
    feat_fast<<<1024, 256, 0, stream>>>(
        d_in[0], d_in[1], d_in[2], d_in[3], d_in[4], d_in[5], d_in[6],
        wb + OFF_PRED, wb + OFF_OP, wb + OFF_BOP, wb + OFF_BPRED, x, flags);
    bm_fast2<<<2048, 256, 0, stream>>>(d_in[7], wb + OFF_WTB, wb + OFF_BBM, x, flags);

    for (int d = DMAX; d >= 0; --d) {
        int count = 1 << d;
        int start = NNODES - (1 << (d + 1)) + 1;
        int isLeaf = (d == DMAX) ? 1 : 0;
        int mc = pick_mc(count);
        int blocks = count / mc;
        switch (mc) {
        case 16: lstm_fast<16><<<blocks, 256, 0, stream>>>(x, wb + OFF_IH, wb + OFF_HH, wb + OFF_B4, H, C, start, isLeaf, flags); break;
        case 8:  lstm_fast<8><<<blocks, 256, 0, stream>>>(x, wb + OFF_IH, wb + OFF_HH, wb + OFF_B4, H, C, start, isLeaf, flags); break;
        case 4:  lstm_fast<4><<<blocks, 256, 0, stream>>>(x, wb + OFF_IH, wb + OFF_HH, wb + OFF_B4, H, C, start, isLeaf, flags); break;
        case 2:  lstm_fast<2><<<blocks, 256, 0, stream>>>(x, wb + OFF_IH, wb + OFF_HH, wb + OFF_B4, H, C, start, isLeaf, flags); break;
        default: lstm_fast<1><<<blocks, 256, 0, stream>>>(x, wb + OFF_IH, wb + OFF_HH, wb + OFF_B4, H, C, start, isLeaf, flags); break;
        }
    }
    heads_kernel<float><<<1, 256, 0, stream>>>(
        H, d_in[18], d_in[19], d_in[20], d_in[21], d_in[22], d_in[23],
        d_in[24], d_in[25], d_in[26], d_in[27], d_in[28], d_in[29],
        d_out, flags);
}

extern "C" void kernel_launch(void* const* d_in, const int* in_sizes, int n_in,
                              void* d_out, int out_size, void* d_ws, size_t ws_size,
                              hipStream_t stream) {
    size_t foff = (ws_size - 64) & ~(size_t)63;     // flags at 64B-aligned tail
    int* flags = (int*)((char*)d_ws + foff);

    probe_kernel<<<1, 1, 0, stream>>>(d_in[0], d_in[14], d_in[7], d_in[2], d_in[3], flags);

    const size_t XHC  = (size_t)NNODES * 800 * 4;   // x+H+C in f32
    const size_t WTOT = (size_t)OFF_TOTAL * 4;      // decoded weights
    if (foff >= XHC + WTOT)  run_fast(d_in, d_out, d_ws, flags, stream);
    else if (foff >= XHC)    run_pipeline<float>(d_in, d_out, d_ws, flags, stream);
    else                     run_pipeline<u16>(d_in, d_out, d_ws, flags, stream);
}